// Round 1
// baseline (5160.669 us; speedup 1.0000x reference)
//
#include <hip/hip_runtime.h>
#include <math.h>

#define Bn 8
#define Cc 512
#define HW 1024
#define HEADS 8
#define HD 64
#define GROUPS 32
#define CPG 16
#define EPS 1e-5f

// ---------------- GroupNorm: one block per (b, group) ----------------
__global__ void gn_kernel(const float* __restrict__ x, const float* __restrict__ gamma,
                          const float* __restrict__ beta, float* __restrict__ hn) {
    int bg = blockIdx.x;               // 0..B*GROUPS-1
    int b = bg / GROUPS, g = bg % GROUPS;
    const int N = CPG * HW;            // 16384 contiguous floats per group
    size_t base = ((size_t)b * Cc + (size_t)g * CPG) * HW;
    const float* xp = x + base;

    float s = 0.f, ss = 0.f;
    for (int i = threadIdx.x; i < N; i += 256) {
        float v = xp[i];
        s += v; ss += v * v;
    }
    __shared__ float red0[4], red1[4];
    for (int off = 32; off > 0; off >>= 1) {
        s  += __shfl_down(s, off);
        ss += __shfl_down(ss, off);
    }
    int wave = threadIdx.x >> 6, lane = threadIdx.x & 63;
    if (lane == 0) { red0[wave] = s; red1[wave] = ss; }
    __syncthreads();
    __shared__ float mean_s, rstd_s;
    if (threadIdx.x == 0) {
        float S  = red0[0] + red0[1] + red0[2] + red0[3];
        float SS = red1[0] + red1[1] + red1[2] + red1[3];
        float mean = S / (float)N;
        float var  = SS / (float)N - mean * mean;
        mean_s = mean;
        rstd_s = rsqrtf(var + EPS);
    }
    __syncthreads();
    float mean = mean_s, rstd = rstd_s;
    for (int i = threadIdx.x; i < N; i += 256) {
        int c = g * CPG + (i >> 10);
        hn[base + i] = (xp[i] - mean) * rstd * gamma[c] + beta[c];
    }
}

// ---------------- Generic tiled fp32 GEMM: Y[b,o,n] = W[o,:]·X[b,:,n] + bias[o] (+resid) ----
template<int M, int K, bool ADD_RESID>
__global__ void gemm_kernel(const float* __restrict__ W, const float* __restrict__ X,
                            const float* __restrict__ bias, const float* __restrict__ resid,
                            float* __restrict__ Y) {
    const int N = HW;
    int bn = blockIdx.x * 64;
    int bm = blockIdx.y * 64;
    int b  = blockIdx.z;
    const float* Xb = X + (size_t)b * K * N;
    __shared__ float Ws[16][64 + 1];   // [k][m]
    __shared__ float Xs[16][64 + 1];   // [k][n]
    int tid = threadIdx.x;             // 256 threads
    int tn = (tid % 16) * 4;
    int tm = (tid / 16) * 4;
    float acc[4][4] = {};
    for (int k0 = 0; k0 < K; k0 += 16) {
        for (int i = tid; i < 1024; i += 256) {
            int m = i >> 4, k = i & 15;
            Ws[k][m] = W[(size_t)(bm + m) * K + (k0 + k)];
        }
        for (int i = tid; i < 1024; i += 256) {
            int k = i >> 6, n = i & 63;
            Xs[k][n] = Xb[(size_t)(k0 + k) * N + (bn + n)];
        }
        __syncthreads();
        #pragma unroll
        for (int k = 0; k < 16; ++k) {
            float wv[4], xv[4];
            #pragma unroll
            for (int u = 0; u < 4; ++u) wv[u] = Ws[k][tm + u];
            #pragma unroll
            for (int u = 0; u < 4; ++u) xv[u] = Xs[k][tn + u];
            #pragma unroll
            for (int i = 0; i < 4; ++i)
                #pragma unroll
                for (int j = 0; j < 4; ++j)
                    acc[i][j] += wv[i] * xv[j];
        }
        __syncthreads();
    }
    #pragma unroll
    for (int i = 0; i < 4; ++i) {
        int o = bm + tm + i;
        float bv = bias[o];
        #pragma unroll
        for (int j = 0; j < 4; ++j) {
            int n = bn + tn + j;
            size_t idx = ((size_t)b * M + o) * N + n;
            float val = acc[i][j] + bv;
            if (ADD_RESID) val += resid[idx];
            Y[idx] = val;
        }
    }
}

// ---------------- Attention: one block (256 thr) per (b, h, query i) ----------------
__global__ void attn_kernel(const float* __restrict__ qkv, float* __restrict__ out) {
    int gid = blockIdx.x;
    int i  = gid % HW;
    int bh = gid / HW;                 // 0..63
    int b = bh / HEADS, h = bh % HEADS;
    const size_t bstride = (size_t)3 * Cc * HW;
    const float* q = qkv + (size_t)b * bstride + ((size_t)(h * HD)) * HW;
    const float* k = qkv + (size_t)b * bstride + ((size_t)(Cc + h * HD)) * HW;
    const float* v = qkv + (size_t)b * bstride + ((size_t)(2 * Cc + h * HD)) * HW;

    __shared__ float qs[HD];
    __shared__ float p[HW];
    __shared__ float red[4];
    __shared__ float m_s, l_s;
    __shared__ float oacc[4][64];

    int tid = threadIdx.x;
    if (tid < HD) qs[tid] = q[(size_t)tid * HW + i];
    __syncthreads();

    const float scale = 0.125f;        // 64^-0.5
    float sloc[4];
    float m = -1e30f;
    #pragma unroll
    for (int u = 0; u < 4; ++u) {
        int j = tid + u * 256;
        float s = 0.f;
        #pragma unroll 8
        for (int c = 0; c < HD; ++c) s += qs[c] * k[(size_t)c * HW + j];
        s *= scale;
        sloc[u] = s;
        m = fmaxf(m, s);
    }
    for (int off = 32; off > 0; off >>= 1) m = fmaxf(m, __shfl_down(m, off));
    int wave = tid >> 6, lane = tid & 63;
    if (lane == 0) red[wave] = m;
    __syncthreads();
    if (tid == 0) m_s = fmaxf(fmaxf(red[0], red[1]), fmaxf(red[2], red[3]));
    __syncthreads();
    m = m_s;
    float l = 0.f;
    #pragma unroll
    for (int u = 0; u < 4; ++u) {
        float e = __expf(sloc[u] - m);
        p[tid + u * 256] = e;
        l += e;
    }
    for (int off = 32; off > 0; off >>= 1) l += __shfl_down(l, off);
    if (lane == 0) red[wave] = l;
    __syncthreads();
    if (tid == 0) l_s = red[0] + red[1] + red[2] + red[3];
    __syncthreads();
    float rl = 1.f / l_s;

    int c = tid & 63;
    int chunk = tid >> 6;
    float acc = 0.f;
    const float* vc = v + (size_t)c * HW;
    int j0 = chunk * 256;
    #pragma unroll 4
    for (int j = j0; j < j0 + 256; ++j) acc += p[j] * vc[j];
    oacc[chunk][c] = acc;
    __syncthreads();
    if (tid < 64) {
        float o = (oacc[0][tid] + oacc[1][tid] + oacc[2][tid] + oacc[3][tid]) * rl;
        out[((size_t)b * Cc + (size_t)(h * HD + tid)) * HW + i] = o;
    }
}

extern "C" void kernel_launch(void* const* d_in, const int* in_sizes, int n_in,
                              void* d_out, int out_size, void* d_ws, size_t ws_size,
                              hipStream_t stream) {
    const float* x      = (const float*)d_in[0];
    const float* gamma  = (const float*)d_in[1];
    const float* beta   = (const float*)d_in[2];
    const float* w_qkv  = (const float*)d_in[3];
    const float* b_qkv  = (const float*)d_in[4];
    const float* w_proj = (const float*)d_in[5];
    const float* b_proj = (const float*)d_in[6];
    float* out = (float*)d_out;

    float* hn   = (float*)d_ws;                      // B*C*HW floats (16 MB)
    float* qkv  = hn + (size_t)Bn * Cc * HW;         // B*3*C*HW floats (48 MB)
    float* attno = hn;                               // reuse hn buffer after QKV GEMM

    gn_kernel<<<Bn * GROUPS, 256, 0, stream>>>(x, gamma, beta, hn);

    dim3 g1(HW / 64, (3 * Cc) / 64, Bn);
    gemm_kernel<3 * Cc, Cc, false><<<g1, 256, 0, stream>>>(w_qkv, hn, b_qkv, nullptr, qkv);

    attn_kernel<<<Bn * HEADS * HW, 256, 0, stream>>>(qkv, attno);

    dim3 g2(HW / 64, Cc / 64, Bn);
    gemm_kernel<Cc, Cc, true><<<g2, 256, 0, stream>>>(w_proj, attno, b_proj, x, out);
}

// Round 2
// 585.576 us; speedup vs baseline: 8.8130x; 8.8130x over previous
//
#include <hip/hip_runtime.h>
#include <math.h>

#define Bn 8
#define Cc 512
#define HW 1024
#define HEADS 8
#define HD 64
#define GROUPS 32
#define CPG 16
#define EPS 1e-5f

typedef float f32x4 __attribute__((ext_vector_type(4)));
typedef __bf16 bf16x8 __attribute__((ext_vector_type(8)));

// ---------------- GroupNorm: one block per (b, group) ----------------
__global__ void gn_kernel(const float* __restrict__ x, const float* __restrict__ gamma,
                          const float* __restrict__ beta, float* __restrict__ hn) {
    int bg = blockIdx.x;               // 0..B*GROUPS-1
    int b = bg / GROUPS, g = bg % GROUPS;
    const int N = CPG * HW;            // 16384 contiguous floats per group
    size_t base = ((size_t)b * Cc + (size_t)g * CPG) * HW;
    const float* xp = x + base;

    float s = 0.f, ss = 0.f;
    for (int i = threadIdx.x; i < N; i += 256) {
        float v = xp[i];
        s += v; ss += v * v;
    }
    __shared__ float red0[4], red1[4];
    for (int off = 32; off > 0; off >>= 1) {
        s  += __shfl_down(s, off);
        ss += __shfl_down(ss, off);
    }
    int wave = threadIdx.x >> 6, lane = threadIdx.x & 63;
    if (lane == 0) { red0[wave] = s; red1[wave] = ss; }
    __syncthreads();
    __shared__ float mean_s, rstd_s;
    if (threadIdx.x == 0) {
        float S  = red0[0] + red0[1] + red0[2] + red0[3];
        float SS = red1[0] + red1[1] + red1[2] + red1[3];
        float mean = S / (float)N;
        float var  = SS / (float)N - mean * mean;
        mean_s = mean;
        rstd_s = rsqrtf(var + EPS);
    }
    __syncthreads();
    float mean = mean_s, rstd = rstd_s;
    for (int i = threadIdx.x; i < N; i += 256) {
        int c = g * CPG + (i >> 10);
        hn[base + i] = (xp[i] - mean) * rstd * gamma[c] + beta[c];
    }
}

// ---------------- Generic tiled fp32 GEMM: Y[b,o,n] = W[o,:]·X[b,:,n] + bias[o] (+resid) ----
template<int M, int K, bool ADD_RESID>
__global__ void gemm_kernel(const float* __restrict__ W, const float* __restrict__ X,
                            const float* __restrict__ bias, const float* __restrict__ resid,
                            float* __restrict__ Y) {
    const int N = HW;
    int bn = blockIdx.x * 64;
    int bm = blockIdx.y * 64;
    int b  = blockIdx.z;
    const float* Xb = X + (size_t)b * K * N;
    __shared__ float Ws[16][64 + 1];   // [k][m]
    __shared__ float Xs[16][64 + 1];   // [k][n]
    int tid = threadIdx.x;             // 256 threads
    int tn = (tid % 16) * 4;
    int tm = (tid / 16) * 4;
    float acc[4][4] = {};
    for (int k0 = 0; k0 < K; k0 += 16) {
        for (int i = tid; i < 1024; i += 256) {
            int m = i >> 4, k = i & 15;
            Ws[k][m] = W[(size_t)(bm + m) * K + (k0 + k)];
        }
        for (int i = tid; i < 1024; i += 256) {
            int k = i >> 6, n = i & 63;
            Xs[k][n] = Xb[(size_t)(k0 + k) * N + (bn + n)];
        }
        __syncthreads();
        #pragma unroll
        for (int k = 0; k < 16; ++k) {
            float wv[4], xv[4];
            #pragma unroll
            for (int u = 0; u < 4; ++u) wv[u] = Ws[k][tm + u];
            #pragma unroll
            for (int u = 0; u < 4; ++u) xv[u] = Xs[k][tn + u];
            #pragma unroll
            for (int i = 0; i < 4; ++i)
                #pragma unroll
                for (int j = 0; j < 4; ++j)
                    acc[i][j] += wv[i] * xv[j];
        }
        __syncthreads();
    }
    #pragma unroll
    for (int i = 0; i < 4; ++i) {
        int o = bm + tm + i;
        float bv = bias[o];
        #pragma unroll
        for (int j = 0; j < 4; ++j) {
            int n = bn + tn + j;
            size_t idx = ((size_t)b * M + o) * N + n;
            float val = acc[i][j] + bv;
            if (ADD_RESID) val += resid[idx];
            Y[idx] = val;
        }
    }
}

// ---------------- Flash attention, bf16 MFMA ----------------
// One block = 256 threads = 4 waves, per (b, h, q-tile of 64 queries).
// Wave w owns the 16-query strip i0 = w*16. K-loop over 16 key tiles of 64.
// Layouts (verified gfx950 16x16x32 bf16):
//   A[m=lane&15][k=quad*8+j], B[k=quad*8+j][n=lane&15], C/D row=quad*4+reg col=lane&15.
// LDS staging: Qs[i][c] (pre-scaled by 1/8), Ks[j][c], Vs[c][j], Ps[i][j] (wave-local).
#define PITCH 72
__global__ __launch_bounds__(256) void attn_mfma(const float* __restrict__ qkv,
                                                 float* __restrict__ out) {
    __shared__ __align__(16) char smem[4 * 64 * PITCH * 2];   // 36864 B
    __bf16* Qs = (__bf16*)smem;
    __bf16* Ks = Qs + 64 * PITCH;
    __bf16* Vs = Ks + 64 * PITCH;
    __bf16* Ps = Vs + 64 * PITCH;
    float*  Os = (float*)smem;                                // overlay after K-loop

    int qt = blockIdx.x & 15;
    int bh = blockIdx.x >> 4;
    int b = bh >> 3, h = bh & 7;
    int qbase = qt * 64;

    const float* qp = qkv + ((size_t)b * 3 * Cc + h * HD) * HW;
    const float* kp = qkv + ((size_t)b * 3 * Cc + Cc + h * HD) * HW;
    const float* vp = qkv + ((size_t)b * 3 * Cc + 2 * Cc + h * HD) * HW;

    int tid = threadIdx.x;
    int wv = tid >> 6;           // wave 0..3 -> i-strip
    int ln = tid & 15;           // lane&15
    int quad = (tid & 63) >> 4;  // lane>>4
    int i0 = wv * 16;

    // ---- stage Q (pre-scaled by hd^-0.5 = 0.125) ----
    #pragma unroll 4
    for (int idx = tid; idx < 4096; idx += 256) {
        int c = idx >> 6, i = idx & 63;
        Qs[i * PITCH + c] = (__bf16)(qp[(size_t)c * HW + qbase + i] * 0.125f);
    }

    f32x4 oacc[4];
    #pragma unroll
    for (int t = 0; t < 4; ++t) oacc[t] = (f32x4){0.f, 0.f, 0.f, 0.f};
    float mrow[4], lrow[4];
    #pragma unroll
    for (int r = 0; r < 4; ++r) { mrow[r] = -1e30f; lrow[r] = 0.f; }

    for (int kt = 0; kt < 16; ++kt) {
        int kbase = kt * 64;
        __syncthreads();   // covers Q-stage on first iter; prev-tile reads after
        #pragma unroll 4
        for (int idx = tid; idx < 4096; idx += 256) {
            int c = idx >> 6, j = idx & 63;
            Ks[j * PITCH + c] = (__bf16)kp[(size_t)c * HW + kbase + j];
            Vs[c * PITCH + j] = (__bf16)vp[(size_t)c * HW + kbase + j];
        }
        __syncthreads();

        // ---- S = Q K^T (pre-scaled) ----
        bf16x8 aq0 = *(const bf16x8*)(Qs + (i0 + ln) * PITCH + quad * 8);
        bf16x8 aq1 = *(const bf16x8*)(Qs + (i0 + ln) * PITCH + 32 + quad * 8);
        f32x4 sacc[4];
        #pragma unroll
        for (int jt = 0; jt < 4; ++jt) {
            bf16x8 bk0 = *(const bf16x8*)(Ks + (jt * 16 + ln) * PITCH + quad * 8);
            bf16x8 bk1 = *(const bf16x8*)(Ks + (jt * 16 + ln) * PITCH + 32 + quad * 8);
            f32x4 s = (f32x4){0.f, 0.f, 0.f, 0.f};
            s = __builtin_amdgcn_mfma_f32_16x16x32_bf16(aq0, bk0, s, 0, 0, 0);
            s = __builtin_amdgcn_mfma_f32_16x16x32_bf16(aq1, bk1, s, 0, 0, 0);
            sacc[jt] = s;
        }

        // ---- online softmax: rows quad*4+r, cols = ln across 16 lanes of quad ----
        float pbuf[4][4];
        #pragma unroll
        for (int r = 0; r < 4; ++r) {
            float rm = fmaxf(fmaxf(sacc[0][r], sacc[1][r]), fmaxf(sacc[2][r], sacc[3][r]));
            rm = fmaxf(rm, __shfl_xor(rm, 1));
            rm = fmaxf(rm, __shfl_xor(rm, 2));
            rm = fmaxf(rm, __shfl_xor(rm, 4));
            rm = fmaxf(rm, __shfl_xor(rm, 8));
            float mn = fmaxf(mrow[r], rm);
            float alpha = __expf(mrow[r] - mn);
            mrow[r] = mn;
            float rs = 0.f;
            #pragma unroll
            for (int jt = 0; jt < 4; ++jt) {
                float p = __expf(sacc[jt][r] - mn);
                pbuf[jt][r] = p;
                rs += p;
            }
            rs += __shfl_xor(rs, 1);
            rs += __shfl_xor(rs, 2);
            rs += __shfl_xor(rs, 4);
            rs += __shfl_xor(rs, 8);
            lrow[r] = alpha * lrow[r] + rs;
            #pragma unroll
            for (int ct = 0; ct < 4; ++ct) oacc[ct][r] *= alpha;
        }

        // ---- P to LDS (wave-local rows: no block sync needed) ----
        #pragma unroll
        for (int jt = 0; jt < 4; ++jt)
            #pragma unroll
            for (int r = 0; r < 4; ++r)
                Ps[(i0 + quad * 4 + r) * PITCH + jt * 16 + ln] = (__bf16)pbuf[jt][r];

        // ---- O += P V ----
        bf16x8 ap0 = *(const bf16x8*)(Ps + (i0 + ln) * PITCH + quad * 8);
        bf16x8 ap1 = *(const bf16x8*)(Ps + (i0 + ln) * PITCH + 32 + quad * 8);
        #pragma unroll
        for (int ct = 0; ct < 4; ++ct) {
            bf16x8 bv0 = *(const bf16x8*)(Vs + (ct * 16 + ln) * PITCH + quad * 8);
            bf16x8 bv1 = *(const bf16x8*)(Vs + (ct * 16 + ln) * PITCH + 32 + quad * 8);
            oacc[ct] = __builtin_amdgcn_mfma_f32_16x16x32_bf16(ap0, bv0, oacc[ct], 0, 0, 0);
            oacc[ct] = __builtin_amdgcn_mfma_f32_16x16x32_bf16(ap1, bv1, oacc[ct], 0, 0, 0);
        }
    }

    // ---- normalize, transpose via LDS, coalesced store ----
    float rl[4];
    #pragma unroll
    for (int r = 0; r < 4; ++r) rl[r] = 1.f / lrow[r];
    __syncthreads();   // all waves done reading Ks/Vs before overlay
    #pragma unroll
    for (int ct = 0; ct < 4; ++ct)
        #pragma unroll
        for (int r = 0; r < 4; ++r)
            Os[(ct * 16 + ln) * 65 + i0 + quad * 4 + r] = oacc[ct][r] * rl[r];
    __syncthreads();
    float* op = out + ((size_t)b * Cc + h * HD) * HW + qbase;
    #pragma unroll 4
    for (int idx = tid; idx < 4096; idx += 256) {
        int c = idx >> 6, ii = idx & 63;
        op[(size_t)c * HW + ii] = Os[c * 65 + ii];
    }
}

extern "C" void kernel_launch(void* const* d_in, const int* in_sizes, int n_in,
                              void* d_out, int out_size, void* d_ws, size_t ws_size,
                              hipStream_t stream) {
    const float* x      = (const float*)d_in[0];
    const float* gamma  = (const float*)d_in[1];
    const float* beta   = (const float*)d_in[2];
    const float* w_qkv  = (const float*)d_in[3];
    const float* b_qkv  = (const float*)d_in[4];
    const float* w_proj = (const float*)d_in[5];
    const float* b_proj = (const float*)d_in[6];
    float* out = (float*)d_out;

    float* hn   = (float*)d_ws;                      // B*C*HW floats (16 MB)
    float* qkv  = hn + (size_t)Bn * Cc * HW;         // B*3*C*HW floats (48 MB)
    float* attno = hn;                               // reuse hn buffer after QKV GEMM

    gn_kernel<<<Bn * GROUPS, 256, 0, stream>>>(x, gamma, beta, hn);

    dim3 g1(HW / 64, (3 * Cc) / 64, Bn);
    gemm_kernel<3 * Cc, Cc, false><<<g1, 256, 0, stream>>>(w_qkv, hn, b_qkv, nullptr, qkv);

    attn_mfma<<<Bn * HEADS * HW / 64, 256, 0, stream>>>(qkv, attno);

    dim3 g2(HW / 64, Cc / 64, Bn);
    gemm_kernel<Cc, Cc, true><<<g2, 256, 0, stream>>>(w_proj, attno, b_proj, x, out);
}

// Round 3
// 267.847 us; speedup vs baseline: 19.2672x; 2.1862x over previous
//
#include <hip/hip_runtime.h>
#include <math.h>

#define Bn 8
#define Cc 512
#define HW 1024
#define HEADS 8
#define HD 64
#define GROUPS 32
#define CPG 16
#define EPS 1e-5f

typedef float f32x4 __attribute__((ext_vector_type(4)));
typedef __bf16 bf16x8 __attribute__((ext_vector_type(8)));
typedef __bf16 bf16x4 __attribute__((ext_vector_type(4)));

__device__ __forceinline__ void async16(const __bf16* g, __bf16* l) {
    __builtin_amdgcn_global_load_lds((const __attribute__((address_space(1))) unsigned int*)g,
                                     (__attribute__((address_space(3))) unsigned int*)l, 16, 0, 0);
}

// ---------------- fp32 -> bf16 weight conversion ----------------
__global__ void conv_kernel(const float* __restrict__ src, __bf16* __restrict__ dst, int n4) {
    int i = blockIdx.x * 256 + threadIdx.x;
    if (i < n4) {
        float4 v = ((const float4*)src)[i];
        bf16x4 o = { (__bf16)v.x, (__bf16)v.y, (__bf16)v.z, (__bf16)v.w };
        ((bf16x4*)dst)[i] = o;
    }
}

// ---------------- GroupNorm -> hnT[b][n][c] bf16 ----------------
__global__ __launch_bounds__(256) void gn_kernel(const float* __restrict__ x,
                                                 const float* __restrict__ gamma,
                                                 const float* __restrict__ beta,
                                                 __bf16* __restrict__ hnT) {
    int bg = blockIdx.x;
    int b = bg >> 5, g = bg & 31;
    const float* xp = x + ((size_t)b * Cc + g * CPG) * HW;
    int tid = threadIdx.x;

    float s = 0.f, ss = 0.f;
    for (int i = tid; i < CPG * HW; i += 256) {
        float v = xp[i];
        s += v; ss += v * v;
    }
    __shared__ float red0[4], red1[4];
    for (int off = 32; off > 0; off >>= 1) {
        s  += __shfl_down(s, off);
        ss += __shfl_down(ss, off);
    }
    int wave = tid >> 6, lane = tid & 63;
    if (lane == 0) { red0[wave] = s; red1[wave] = ss; }
    __syncthreads();
    __shared__ float mean_s, rstd_s;
    if (tid == 0) {
        float S  = red0[0] + red0[1] + red0[2] + red0[3];
        float SS = red1[0] + red1[1] + red1[2] + red1[3];
        float mean = S / (float)(CPG * HW);
        float var  = SS / (float)(CPG * HW) - mean * mean;
        mean_s = mean;
        rstd_s = rsqrtf(var + EPS);
    }
    __syncthreads();
    float mean = mean_s, rstd = rstd_s;

    __shared__ float tile[16 * 257];
    for (int chunk = 0; chunk < 4; ++chunk) {
        __syncthreads();
        for (int i = tid; i < 4096; i += 256) {
            int c = i >> 8, n = i & 255;
            float v = xp[(size_t)c * HW + chunk * 256 + n];
            tile[c * 257 + n] = (v - mean) * rstd * gamma[g * CPG + c] + beta[g * CPG + c];
        }
        __syncthreads();
        int n = chunk * 256 + tid;
        union { __bf16 bs[16]; uint4 q[2]; } u;
        #pragma unroll
        for (int c = 0; c < 16; ++c) u.bs[c] = (__bf16)tile[c * 257 + tid];
        uint4* dst = (uint4*)(hnT + ((size_t)b * HW + n) * Cc + g * CPG);
        dst[0] = u.q[0];
        dst[1] = u.q[1];
    }
}

// ---------------- MFMA GEMM: D[m][n] = sum_k P[m][k] * Q[n][k] ----------------
// P: M x 512 row-major (K-contig), Q: N x 512 row-major (K-contig). bf16.
// 128x128 tile, 256 thr = 4 waves, each wave 64x64 (4x4 of 16x16x32 MFMA).
// Staging via global_load_lds width=16, XOR-swizzled chunks (2-way conflicts only).
template<bool BIAS_COL, bool RESID_F32>
__global__ __launch_bounds__(256) void gemm_mfma(
    const __bf16* __restrict__ Pm, const __bf16* __restrict__ Qm,
    const float* __restrict__ bias, const float* __restrict__ resid,
    void* __restrict__ outv, size_t pStride, size_t qStride, size_t oStride, int oN) {
    __shared__ __bf16 As[128 * 64];
    __shared__ __bf16 Bs[128 * 64];
    int tid = threadIdx.x;
    int wv = tid >> 6, lane = tid & 63, ln = lane & 15, quad = lane >> 4;
    int lr = lane >> 3, lc = lane & 7;
    int b = blockIdx.z;
    int bm = blockIdx.y * 128, bn = blockIdx.x * 128;
    const __bf16* Pb = Pm + (size_t)b * pStride;
    const __bf16* Qb = Qm + (size_t)b * qStride;
    int wm = (wv >> 1) * 64, wn = (wv & 1) * 64;

    f32x4 acc[4][4];
    #pragma unroll
    for (int i = 0; i < 4; ++i)
        #pragma unroll
        for (int j = 0; j < 4; ++j) acc[i][j] = (f32x4){0.f, 0.f, 0.f, 0.f};

    for (int k0 = 0; k0 < 512; k0 += 64) {
        __syncthreads();
        #pragma unroll
        for (int u = 0; u < 4; ++u) {
            int r = wv * 32 + u * 8 + lr;
            int cg = lc ^ (r & 7);
            async16(Pb + (size_t)(bm + r) * 512 + k0 + cg * 8, &As[r * 64 + lc * 8]);
            async16(Qb + (size_t)(bn + r) * 512 + k0 + cg * 8, &Bs[r * 64 + lc * 8]);
        }
        __syncthreads();
        bf16x8 af[4][2], bff[4][2];
        #pragma unroll
        for (int mt = 0; mt < 4; ++mt) {
            int row = wm + mt * 16 + ln;
            #pragma unroll
            for (int h = 0; h < 2; ++h) {
                int cc = (h * 4 + quad) ^ (ln & 7);
                af[mt][h] = *(const bf16x8*)&As[row * 64 + cc * 8];
            }
        }
        #pragma unroll
        for (int nt = 0; nt < 4; ++nt) {
            int row = wn + nt * 16 + ln;
            #pragma unroll
            for (int h = 0; h < 2; ++h) {
                int cc = (h * 4 + quad) ^ (ln & 7);
                bff[nt][h] = *(const bf16x8*)&Bs[row * 64 + cc * 8];
            }
        }
        #pragma unroll
        for (int mt = 0; mt < 4; ++mt)
            #pragma unroll
            for (int nt = 0; nt < 4; ++nt) {
                acc[mt][nt] = __builtin_amdgcn_mfma_f32_16x16x32_bf16(af[mt][0], bff[nt][0], acc[mt][nt], 0, 0, 0);
                acc[mt][nt] = __builtin_amdgcn_mfma_f32_16x16x32_bf16(af[mt][1], bff[nt][1], acc[mt][nt], 0, 0, 0);
            }
    }

    // epilogue: C/D layout row = quad*4 + r, col = ln
    if (RESID_F32) {
        float* out = (float*)outv + (size_t)b * oStride;
        const float* res = resid + (size_t)b * oStride;
        #pragma unroll
        for (int mt = 0; mt < 4; ++mt)
            #pragma unroll
            for (int r = 0; r < 4; ++r) {
                int row = bm + wm + mt * 16 + quad * 4 + r;
                float bv = bias[row];
                #pragma unroll
                for (int nt = 0; nt < 4; ++nt) {
                    int col = bn + wn + nt * 16 + ln;
                    size_t idx = (size_t)row * oN + col;
                    out[idx] = acc[mt][nt][r] + bv + res[idx];
                }
            }
    } else {
        __bf16* out = (__bf16*)outv + (size_t)b * oStride;
        float bcol[4];
        if (BIAS_COL) {
            #pragma unroll
            for (int nt = 0; nt < 4; ++nt) bcol[nt] = bias[bn + wn + nt * 16 + ln];
        }
        #pragma unroll
        for (int mt = 0; mt < 4; ++mt)
            #pragma unroll
            for (int r = 0; r < 4; ++r) {
                int row = bm + wm + mt * 16 + quad * 4 + r;
                float brow = BIAS_COL ? 0.f : bias[row];
                #pragma unroll
                for (int nt = 0; nt < 4; ++nt) {
                    int col = bn + wn + nt * 16 + ln;
                    float bv = BIAS_COL ? bcol[nt] : brow;
                    out[(size_t)row * oN + col] = (__bf16)(acc[mt][nt][r] + bv);
                }
            }
    }
}

// ---------------- Flash attention, all-global MFMA fragments ----------------
// qkT[b][n][o]: Q cols 0..511 (h*64+c), K cols 512..1023. v[b][c][n] natural.
// One wave per (b, h, 16-query strip). No block-level syncs; P via wave-local LDS.
#define PP 68
__global__ __launch_bounds__(256) void attn_mfma(const __bf16* __restrict__ qkT,
                                                 const __bf16* __restrict__ vbuf,
                                                 __bf16* __restrict__ attnT) {
    __shared__ __bf16 Ps[4][16 * PP];
    int tid = threadIdx.x;
    int wv = tid >> 6, lane = tid & 63, ln = lane & 15, quad = lane >> 4;
    int W = blockIdx.x * 4 + wv;
    int strip = W & 63, bh = W >> 6;
    int b = bh >> 3, h = bh & 7;
    int i0 = strip * 16;

    const __bf16* qb = qkT + (size_t)b * HW * 1024;
    const __bf16* qrow = qb + (size_t)(i0 + ln) * 1024 + h * HD + quad * 8;
    bf16x8 aq0 = *(const bf16x8*)qrow;
    bf16x8 aq1 = *(const bf16x8*)(qrow + 32);
    const __bf16* kbase_p = qb + 512 + h * HD + quad * 8;          // + j*1024
    const __bf16* vrow = vbuf + (size_t)b * Cc * HW + (size_t)(h * HD + ln) * HW + quad * 8;
    __bf16* P = &Ps[wv][0];

    f32x4 oacc[4];
    #pragma unroll
    for (int t = 0; t < 4; ++t) oacc[t] = (f32x4){0.f, 0.f, 0.f, 0.f};
    float mrow[4], lrow[4];
    #pragma unroll
    for (int r = 0; r < 4; ++r) { mrow[r] = -3e38f; lrow[r] = 0.f; }

    for (int kt = 0; kt < 16; ++kt) {
        int kb = kt * 64;
        f32x4 sacc[4];
        #pragma unroll
        for (int jt = 0; jt < 4; ++jt) {
            const __bf16* kr = kbase_p + (size_t)(kb + jt * 16 + ln) * 1024;
            bf16x8 bk0 = *(const bf16x8*)kr;
            bf16x8 bk1 = *(const bf16x8*)(kr + 32);
            f32x4 s = (f32x4){0.f, 0.f, 0.f, 0.f};
            s = __builtin_amdgcn_mfma_f32_16x16x32_bf16(aq0, bk0, s, 0, 0, 0);
            s = __builtin_amdgcn_mfma_f32_16x16x32_bf16(aq1, bk1, s, 0, 0, 0);
            sacc[jt] = s;
        }
        #pragma unroll
        for (int jt = 0; jt < 4; ++jt) sacc[jt] *= 0.125f;

        #pragma unroll
        for (int r = 0; r < 4; ++r) {
            float rm = fmaxf(fmaxf(sacc[0][r], sacc[1][r]), fmaxf(sacc[2][r], sacc[3][r]));
            rm = fmaxf(rm, __shfl_xor(rm, 1));
            rm = fmaxf(rm, __shfl_xor(rm, 2));
            rm = fmaxf(rm, __shfl_xor(rm, 4));
            rm = fmaxf(rm, __shfl_xor(rm, 8));
            float mn = fmaxf(mrow[r], rm);
            float alpha = __expf(mrow[r] - mn);
            mrow[r] = mn;
            float rs = 0.f;
            #pragma unroll
            for (int jt = 0; jt < 4; ++jt) {
                float p = __expf(sacc[jt][r] - mn);
                P[(quad * 4 + r) * PP + jt * 16 + ln] = (__bf16)p;
                rs += p;
            }
            rs += __shfl_xor(rs, 1);
            rs += __shfl_xor(rs, 2);
            rs += __shfl_xor(rs, 4);
            rs += __shfl_xor(rs, 8);
            lrow[r] = alpha * lrow[r] + rs;
            #pragma unroll
            for (int ct = 0; ct < 4; ++ct) oacc[ct][r] *= alpha;
        }

        bf16x8 ap0 = *(const bf16x8*)(P + ln * PP + quad * 8);
        bf16x8 ap1 = *(const bf16x8*)(P + ln * PP + 32 + quad * 8);
        #pragma unroll
        for (int ct = 0; ct < 4; ++ct) {
            const __bf16* vr = vrow + (size_t)(ct * 16) * HW + kb;
            bf16x8 bv0 = *(const bf16x8*)vr;
            bf16x8 bv1 = *(const bf16x8*)(vr + 32);
            oacc[ct] = __builtin_amdgcn_mfma_f32_16x16x32_bf16(ap0, bv0, oacc[ct], 0, 0, 0);
            oacc[ct] = __builtin_amdgcn_mfma_f32_16x16x32_bf16(ap1, bv1, oacc[ct], 0, 0, 0);
        }
    }

    float rl[4];
    #pragma unroll
    for (int r = 0; r < 4; ++r) rl[r] = 1.f / lrow[r];
    #pragma unroll
    for (int ct = 0; ct < 4; ++ct)
        #pragma unroll
        for (int r = 0; r < 4; ++r) {
            size_t idx = ((size_t)b * HW + i0 + quad * 4 + r) * Cc + h * HD + ct * 16 + ln;
            attnT[idx] = (__bf16)(oacc[ct][r] * rl[r]);
        }
}

extern "C" void kernel_launch(void* const* d_in, const int* in_sizes, int n_in,
                              void* d_out, int out_size, void* d_ws, size_t ws_size,
                              hipStream_t stream) {
    const float* x      = (const float*)d_in[0];
    const float* gamma  = (const float*)d_in[1];
    const float* beta   = (const float*)d_in[2];
    const float* w_qkv  = (const float*)d_in[3];
    const float* b_qkv  = (const float*)d_in[4];
    const float* w_proj = (const float*)d_in[5];
    const float* b_proj = (const float*)d_in[6];
    float* out = (float*)d_out;

    __bf16* wq_bf  = (__bf16*)d_ws;                       // 1536*512
    __bf16* wp_bf  = wq_bf + (size_t)1536 * 512;          // 512*512
    __bf16* hnT    = wp_bf + (size_t)512 * 512;           // B*1024*512
    __bf16* qkT    = hnT + (size_t)Bn * HW * Cc;          // B*1024*1024
    __bf16* vbuf   = qkT + (size_t)Bn * HW * 1024;        // B*512*1024
    __bf16* attnT  = vbuf + (size_t)Bn * Cc * HW;         // B*1024*512

    conv_kernel<<<768, 256, 0, stream>>>(w_qkv, wq_bf, 1536 * 512 / 4);
    conv_kernel<<<256, 256, 0, stream>>>(w_proj, wp_bf, 512 * 512 / 4);

    gn_kernel<<<Bn * GROUPS, 256, 0, stream>>>(x, gamma, beta, hnT);

    // QK: D[n][o] = sum_c hnT[n][c] * w_qkv[o][c] + b_qkv[o], o in [0,1024)
    dim3 gqk(8, 8, Bn);
    gemm_mfma<true, false><<<gqk, 256, 0, stream>>>(
        hnT, wq_bf, b_qkv, nullptr, qkT,
        (size_t)HW * Cc, 0, (size_t)HW * 1024, 1024);

    // V: D[vo][n] = sum_c w_qkv[1024+vo][c] * hnT[n][c] + b_qkv[1024+vo]
    dim3 gv(8, 4, Bn);
    gemm_mfma<false, false><<<gv, 256, 0, stream>>>(
        wq_bf + (size_t)1024 * 512, hnT, b_qkv + 1024, nullptr, vbuf,
        0, (size_t)HW * Cc, (size_t)Cc * HW, 1024);

    attn_mfma<<<Bn * HEADS * 64 / 4, 256, 0, stream>>>(qkT, vbuf, attnT);

    // proj: D[o][n] = sum_c w_proj[o][c] * attnT[n][c] + b_proj[o] + x
    dim3 gp(8, 4, Bn);
    gemm_mfma<false, true><<<gp, 256, 0, stream>>>(
        wp_bf, attnT, b_proj, x, out,
        0, (size_t)HW * Cc, (size_t)Cc * HW, 1024);
}

// Round 5
// 190.173 us; speedup vs baseline: 27.1367x; 1.4084x over previous
//
#include <hip/hip_runtime.h>
#include <math.h>

#define Bn 8
#define Cc 512
#define HW 1024
#define HEADS 8
#define HD 64
#define GROUPS 32
#define CPG 16
#define EPS 1e-5f

typedef float f32x4 __attribute__((ext_vector_type(4)));
typedef __bf16 bf16x8 __attribute__((ext_vector_type(8)));
typedef __bf16 bf16x4 __attribute__((ext_vector_type(4)));
typedef short s16x4 __attribute__((ext_vector_type(4)));

__device__ __forceinline__ void async16(const __bf16* g, __bf16* l) {
    __builtin_amdgcn_global_load_lds((const __attribute__((address_space(1))) unsigned int*)g,
                                     (__attribute__((address_space(3))) unsigned int*)l, 16, 0, 0);
}

__device__ __forceinline__ f32x4 mfma16(bf16x4 a, bf16x4 b, f32x4 c) {
    return __builtin_amdgcn_mfma_f32_16x16x16bf16_1k(
        __builtin_bit_cast(s16x4, a), __builtin_bit_cast(s16x4, b), c, 0, 0, 0);
}

// ---------------- fp32 -> bf16 weight conversion ----------------
__global__ void conv_kernel(const float* __restrict__ src, __bf16* __restrict__ dst, int n4) {
    int i = blockIdx.x * 256 + threadIdx.x;
    if (i < n4) {
        float4 v = ((const float4*)src)[i];
        bf16x4 o = { (__bf16)v.x, (__bf16)v.y, (__bf16)v.z, (__bf16)v.w };
        ((bf16x4*)dst)[i] = o;
    }
}

// ---------------- GroupNorm -> hnT[b][n][c] bf16 ----------------
__global__ __launch_bounds__(256) void gn_kernel(const float* __restrict__ x,
                                                 const float* __restrict__ gamma,
                                                 const float* __restrict__ beta,
                                                 __bf16* __restrict__ hnT) {
    int bg = blockIdx.x;
    int b = bg >> 5, g = bg & 31;
    const float* xp = x + ((size_t)b * Cc + g * CPG) * HW;
    int tid = threadIdx.x;

    float s = 0.f, ss = 0.f;
    for (int i = tid; i < CPG * HW; i += 256) {
        float v = xp[i];
        s += v; ss += v * v;
    }
    __shared__ float red0[4], red1[4];
    for (int off = 32; off > 0; off >>= 1) {
        s  += __shfl_down(s, off);
        ss += __shfl_down(ss, off);
    }
    int wave = tid >> 6, lane = tid & 63;
    if (lane == 0) { red0[wave] = s; red1[wave] = ss; }
    __syncthreads();
    __shared__ float mean_s, rstd_s;
    if (tid == 0) {
        float S  = red0[0] + red0[1] + red0[2] + red0[3];
        float SS = red1[0] + red1[1] + red1[2] + red1[3];
        float mean = S / (float)(CPG * HW);
        float var  = SS / (float)(CPG * HW) - mean * mean;
        mean_s = mean;
        rstd_s = rsqrtf(var + EPS);
    }
    __syncthreads();
    float mean = mean_s, rstd = rstd_s;

    __shared__ float tile[16 * 257];
    for (int chunk = 0; chunk < 4; ++chunk) {
        __syncthreads();
        for (int i = tid; i < 4096; i += 256) {
            int c = i >> 8, n = i & 255;
            float v = xp[(size_t)c * HW + chunk * 256 + n];
            tile[c * 257 + n] = (v - mean) * rstd * gamma[g * CPG + c] + beta[g * CPG + c];
        }
        __syncthreads();
        int n = chunk * 256 + tid;
        union { __bf16 bs[16]; uint4 q[2]; } u;
        #pragma unroll
        for (int c = 0; c < 16; ++c) u.bs[c] = (__bf16)tile[c * 257 + tid];
        uint4* dst = (uint4*)(hnT + ((size_t)b * HW + n) * Cc + g * CPG);
        dst[0] = u.q[0];
        dst[1] = u.q[1];
    }
}

// ---------------- MFMA GEMM: D[m][n] = sum_k P[m][k] * Q[n][k] ----------------
template<bool BIAS_COL, bool RESID_F32>
__global__ __launch_bounds__(256) void gemm_mfma(
    const __bf16* __restrict__ Pm, const __bf16* __restrict__ Qm,
    const float* __restrict__ bias, const float* __restrict__ resid,
    void* __restrict__ outv, size_t pStride, size_t qStride, size_t oStride, int oN,
    float scaleLo, int loCols) {
    __shared__ __align__(16) __bf16 As[128 * 64];
    __shared__ __align__(16) __bf16 Bs[128 * 64];
    int tid = threadIdx.x;
    int wv = tid >> 6, lane = tid & 63, ln = lane & 15, quad = lane >> 4;
    int lr = lane >> 3, lc = lane & 7;
    int b = blockIdx.z;
    int bm = blockIdx.y * 128, bn = blockIdx.x * 128;
    const __bf16* Pb = Pm + (size_t)b * pStride;
    const __bf16* Qb = Qm + (size_t)b * qStride;
    int wm = (wv >> 1) * 64, wn = (wv & 1) * 64;

    f32x4 acc[4][4];
    #pragma unroll
    for (int i = 0; i < 4; ++i)
        #pragma unroll
        for (int j = 0; j < 4; ++j) acc[i][j] = (f32x4){0.f, 0.f, 0.f, 0.f};

    for (int k0 = 0; k0 < 512; k0 += 64) {
        __syncthreads();
        #pragma unroll
        for (int u = 0; u < 4; ++u) {
            int r = wv * 32 + u * 8 + lr;
            int cg = lc ^ (r & 7);
            async16(Pb + (size_t)(bm + r) * 512 + k0 + cg * 8, &As[r * 64 + lc * 8]);
            async16(Qb + (size_t)(bn + r) * 512 + k0 + cg * 8, &Bs[r * 64 + lc * 8]);
        }
        __syncthreads();
        bf16x8 af[4][2], bff[4][2];
        #pragma unroll
        for (int mt = 0; mt < 4; ++mt) {
            int row = wm + mt * 16 + ln;
            #pragma unroll
            for (int h = 0; h < 2; ++h) {
                int cc = (h * 4 + quad) ^ (ln & 7);
                af[mt][h] = *(const bf16x8*)&As[row * 64 + cc * 8];
            }
        }
        #pragma unroll
        for (int nt = 0; nt < 4; ++nt) {
            int row = wn + nt * 16 + ln;
            #pragma unroll
            for (int h = 0; h < 2; ++h) {
                int cc = (h * 4 + quad) ^ (ln & 7);
                bff[nt][h] = *(const bf16x8*)&Bs[row * 64 + cc * 8];
            }
        }
        #pragma unroll
        for (int mt = 0; mt < 4; ++mt)
            #pragma unroll
            for (int nt = 0; nt < 4; ++nt) {
                acc[mt][nt] = __builtin_amdgcn_mfma_f32_16x16x32_bf16(af[mt][0], bff[nt][0], acc[mt][nt], 0, 0, 0);
                acc[mt][nt] = __builtin_amdgcn_mfma_f32_16x16x32_bf16(af[mt][1], bff[nt][1], acc[mt][nt], 0, 0, 0);
            }
    }

    if (RESID_F32) {
        float* out = (float*)outv + (size_t)b * oStride;
        const float* res = resid + (size_t)b * oStride;
        #pragma unroll
        for (int mt = 0; mt < 4; ++mt)
            #pragma unroll
            for (int r = 0; r < 4; ++r) {
                int row = bm + wm + mt * 16 + quad * 4 + r;
                float bv = bias[row];
                #pragma unroll
                for (int nt = 0; nt < 4; ++nt) {
                    int col = bn + wn + nt * 16 + ln;
                    size_t idx = (size_t)row * oN + col;
                    out[idx] = acc[mt][nt][r] + bv + res[idx];
                }
            }
    } else {
        __bf16* out = (__bf16*)outv + (size_t)b * oStride;
        float bcol[4], scol[4];
        if (BIAS_COL) {
            #pragma unroll
            for (int nt = 0; nt < 4; ++nt) {
                int col = bn + wn + nt * 16 + ln;
                bcol[nt] = bias[col];
                scol[nt] = (col < loCols) ? scaleLo : 1.0f;
            }
        }
        #pragma unroll
        for (int mt = 0; mt < 4; ++mt)
            #pragma unroll
            for (int r = 0; r < 4; ++r) {
                int row = bm + wm + mt * 16 + quad * 4 + r;
                float brow = BIAS_COL ? 0.f : bias[row];
                #pragma unroll
                for (int nt = 0; nt < 4; ++nt) {
                    int col = bn + wn + nt * 16 + ln;
                    float v = BIAS_COL ? (acc[mt][nt][r] + bcol[nt]) * scol[nt]
                                       : acc[mt][nt][r] + brow;
                    out[(size_t)row * oN + col] = (__bf16)v;
                }
            }
    }
}

// ---------------- Flash attention v2: S^T trick, P in registers ----------------
// Grid (8 qblocks, 64 bh). Block: 4 waves, each wave 32 queries (2 strips of 16).
// K/V tiles staged in LDS (global_load_lds w16, XOR-swizzled). Max-free softmax:
// Q pre-scaled by 0.125*log2e in QK-GEMM epilogue, p = exp2(s_raw).
// S^T = MFMA32(A=K, B=Q): C-layout row=j(quad*4+r), col=i(ln) == B-frag layout of
// 16x16x16 MFMA -> PV as O^T = MFMA16(A=V, B=P^T) with P never leaving registers.
__global__ __launch_bounds__(256) void attn_mfma(const __bf16* __restrict__ qkT,
                                                 const __bf16* __restrict__ vbuf,
                                                 __bf16* __restrict__ attnT) {
    __shared__ __align__(16) __bf16 Ks[64 * 64];
    __shared__ __align__(16) __bf16 Vs[64 * 64];
    int tid = threadIdx.x;
    int wv = tid >> 6, lane = tid & 63, ln = lane & 15, quad = lane >> 4;
    int bh = blockIdx.y;
    int b = bh >> 3, h = bh & 7;
    int i0 = blockIdx.x * 128 + wv * 32;

    // Q fragments (B-operand): strip mt rows i0+mt*16+ln, cols h*64 + quad*8 (+32)
    const __bf16* qbase = qkT + ((size_t)b * HW + i0 + ln) * 1024 + h * HD + quad * 8;
    bf16x8 qf[2][2];
    #pragma unroll
    for (int mt = 0; mt < 2; ++mt) {
        qf[mt][0] = *(const bf16x8*)(qbase + (size_t)mt * 16 * 1024);
        qf[mt][1] = *(const bf16x8*)(qbase + (size_t)mt * 16 * 1024 + 32);
    }

    f32x4 oacc[2][4];
    #pragma unroll
    for (int mt = 0; mt < 2; ++mt)
        #pragma unroll
        for (int ct = 0; ct < 4; ++ct) oacc[mt][ct] = (f32x4){0.f, 0.f, 0.f, 0.f};
    float lsum[2] = {0.f, 0.f};

    for (int kt = 0; kt < 16; ++kt) {
        int kb = kt * 64;
        __syncthreads();
        // stage K tile (64 keys x 64 ch) and V tile (64 ch x 64 keys)
        #pragma unroll
        for (int u = 0; u < 2; ++u) {
            int idx = u * 256 + tid;
            int r = idx >> 3, lc = idx & 7;
            int cg = lc ^ (r & 7);
            async16(qkT + ((size_t)b * HW + kb + r) * 1024 + 512 + h * HD + cg * 8,
                    Ks + idx * 8);
            async16(vbuf + ((size_t)b * Cc + h * HD + r) * HW + kb + cg * 8,
                    Vs + idx * 8);
        }
        __syncthreads();

        // ---- S^T[j][i] = sum_c K[j][c] * Qs[i][c]  (Q carries 0.125*log2e) ----
        f32x4 st[2][4];
        #pragma unroll
        for (int jt = 0; jt < 4; ++jt) {
            int row = jt * 16 + ln;
            int c0 = quad ^ (ln & 7);
            int c1 = (4 + quad) ^ (ln & 7);
            bf16x8 kf0 = *(const bf16x8*)&Ks[row * 64 + c0 * 8];
            bf16x8 kf1 = *(const bf16x8*)&Ks[row * 64 + c1 * 8];
            #pragma unroll
            for (int mt = 0; mt < 2; ++mt) {
                f32x4 s = (f32x4){0.f, 0.f, 0.f, 0.f};
                s = __builtin_amdgcn_mfma_f32_16x16x32_bf16(kf0, qf[mt][0], s, 0, 0, 0);
                s = __builtin_amdgcn_mfma_f32_16x16x32_bf16(kf1, qf[mt][1], s, 0, 0, 0);
                st[mt][jt] = s;
            }
        }

        // ---- p = exp2(s); per-lane row-sum accumulate; pack to bf16x4 (B-frag of mfma16) ----
        bf16x4 pk[2][4];
        #pragma unroll
        for (int mt = 0; mt < 2; ++mt)
            #pragma unroll
            for (int jt = 0; jt < 4; ++jt) {
                float p0 = exp2f(st[mt][jt][0]);
                float p1 = exp2f(st[mt][jt][1]);
                float p2 = exp2f(st[mt][jt][2]);
                float p3 = exp2f(st[mt][jt][3]);
                lsum[mt] += (p0 + p1) + (p2 + p3);
                pk[mt][jt] = (bf16x4){(__bf16)p0, (__bf16)p1, (__bf16)p2, (__bf16)p3};
            }

        // ---- O^T[c][i] += sum_j V[c][j] * P^T[j][i] ----
        #pragma unroll
        for (int ct = 0; ct < 4; ++ct) {
            int row = ct * 16 + ln;
            bf16x4 vf[4];
            #pragma unroll
            for (int ks = 0; ks < 4; ++ks) {
                int cc16 = (ks * 2 + (quad >> 1)) ^ (ln & 7);
                vf[ks] = *(const bf16x4*)&Vs[row * 64 + cc16 * 8 + (quad & 1) * 4];
            }
            #pragma unroll
            for (int mt = 0; mt < 2; ++mt)
                #pragma unroll
                for (int ks = 0; ks < 4; ++ks)
                    oacc[mt][ct] = mfma16(vf[ks], pk[mt][ks], oacc[mt][ct]);
        }
    }

    // ---- final row-sum reduce (once), normalize, store O^T -> attnT[n][c] ----
    #pragma unroll
    for (int mt = 0; mt < 2; ++mt) {
        lsum[mt] += __shfl_xor(lsum[mt], 16);
        lsum[mt] += __shfl_xor(lsum[mt], 32);
    }
    #pragma unroll
    for (int mt = 0; mt < 2; ++mt) {
        float rl = 1.f / lsum[mt];
        __bf16* op = attnT + ((size_t)b * HW + i0 + mt * 16 + ln) * Cc + h * HD + quad * 4;
        #pragma unroll
        for (int ct = 0; ct < 4; ++ct) {
            bf16x4 o = { (__bf16)(oacc[mt][ct][0] * rl), (__bf16)(oacc[mt][ct][1] * rl),
                         (__bf16)(oacc[mt][ct][2] * rl), (__bf16)(oacc[mt][ct][3] * rl) };
            *(bf16x4*)(op + ct * 16) = o;
        }
    }
}

extern "C" void kernel_launch(void* const* d_in, const int* in_sizes, int n_in,
                              void* d_out, int out_size, void* d_ws, size_t ws_size,
                              hipStream_t stream) {
    const float* x      = (const float*)d_in[0];
    const float* gamma  = (const float*)d_in[1];
    const float* beta   = (const float*)d_in[2];
    const float* w_qkv  = (const float*)d_in[3];
    const float* b_qkv  = (const float*)d_in[4];
    const float* w_proj = (const float*)d_in[5];
    const float* b_proj = (const float*)d_in[6];
    float* out = (float*)d_out;

    __bf16* wq_bf  = (__bf16*)d_ws;                       // 1536*512
    __bf16* wp_bf  = wq_bf + (size_t)1536 * 512;          // 512*512
    __bf16* hnT    = wp_bf + (size_t)512 * 512;           // B*1024*512
    __bf16* qkT    = hnT + (size_t)Bn * HW * Cc;          // B*1024*1024
    __bf16* vbuf   = qkT + (size_t)Bn * HW * 1024;        // B*512*1024
    __bf16* attnT  = vbuf + (size_t)Bn * Cc * HW;         // B*1024*512

    conv_kernel<<<768, 256, 0, stream>>>(w_qkv, wq_bf, 1536 * 512 / 4);
    conv_kernel<<<256, 256, 0, stream>>>(w_proj, wp_bf, 512 * 512 / 4);

    gn_kernel<<<Bn * GROUPS, 256, 0, stream>>>(x, gamma, beta, hnT);

    // QK: D[n][o] = sum_c hnT[n][c] * w_qkv[o][c] + b_qkv[o]; Q cols (<512) pre-scaled
    const float QSCALE = 0.125f * 1.44269504088896f;  // hd^-0.5 * log2(e)
    dim3 gqk(8, 8, Bn);
    gemm_mfma<true, false><<<gqk, 256, 0, stream>>>(
        hnT, wq_bf, b_qkv, nullptr, qkT,
        (size_t)HW * Cc, 0, (size_t)HW * 1024, 1024, QSCALE, 512);

    // V: D[vo][n] = sum_c w_qkv[1024+vo][c] * hnT[n][c] + b_qkv[1024+vo]
    dim3 gv(8, 4, Bn);
    gemm_mfma<false, false><<<gv, 256, 0, stream>>>(
        wq_bf + (size_t)1024 * 512, hnT, b_qkv + 1024, nullptr, vbuf,
        0, (size_t)HW * Cc, (size_t)Cc * HW, 1024, 1.0f, 0);

    dim3 ga(8, 64);
    attn_mfma<<<ga, 256, 0, stream>>>(qkT, vbuf, attnT);

    // proj: D[o][n] = sum_c w_proj[o][c] * attnT[n][c] + b_proj[o] + x
    dim3 gp(8, 4, Bn);
    gemm_mfma<false, true><<<gp, 256, 0, stream>>>(
        wp_bf, attnT, b_proj, x, out,
        0, (size_t)HW * Cc, (size_t)Cc * HW, 1024, 1.0f, 0);
}

// Round 6
// 186.357 us; speedup vs baseline: 27.6924x; 1.0205x over previous
//
#include <hip/hip_runtime.h>
#include <math.h>

#define Bn 8
#define Cc 512
#define HW 1024
#define HEADS 8
#define HD 64
#define GROUPS 32
#define CPG 16
#define EPS 1e-5f

typedef float f32x4 __attribute__((ext_vector_type(4)));
typedef __bf16 bf16x8 __attribute__((ext_vector_type(8)));
typedef __bf16 bf16x4 __attribute__((ext_vector_type(4)));
typedef short s16x4 __attribute__((ext_vector_type(4)));

__device__ __forceinline__ void async16(const __bf16* g, __bf16* l) {
    __builtin_amdgcn_global_load_lds((const __attribute__((address_space(1))) unsigned int*)g,
                                     (__attribute__((address_space(3))) unsigned int*)l, 16, 0, 0);
}

__device__ __forceinline__ f32x4 mfma16(bf16x4 a, bf16x4 b, f32x4 c) {
    return __builtin_amdgcn_mfma_f32_16x16x16bf16_1k(
        __builtin_bit_cast(s16x4, a), __builtin_bit_cast(s16x4, b), c, 0, 0, 0);
}

// ---------------- fp32 -> bf16 weight conversion (both weights, one launch) ----------------
__global__ void conv_kernel(const float* __restrict__ a, __bf16* __restrict__ da, int na4,
                            const float* __restrict__ b, __bf16* __restrict__ db, int nb4) {
    int i = blockIdx.x * 256 + threadIdx.x;
    if (i < na4) {
        float4 v = ((const float4*)a)[i];
        bf16x4 o = { (__bf16)v.x, (__bf16)v.y, (__bf16)v.z, (__bf16)v.w };
        ((bf16x4*)da)[i] = o;
    } else {
        int j = i - na4;
        if (j < nb4) {
            float4 v = ((const float4*)b)[j];
            bf16x4 o = { (__bf16)v.x, (__bf16)v.y, (__bf16)v.z, (__bf16)v.w };
            ((bf16x4*)db)[j] = o;
        }
    }
}

// ---------------- GroupNorm stats: one block per (b, group) ----------------
__global__ __launch_bounds__(256) void gn_stats(const float* __restrict__ x,
                                                float* __restrict__ gstats) {
    int bg = blockIdx.x;
    int b = bg >> 5, g = bg & 31;
    const float* xp = x + ((size_t)b * Cc + g * CPG) * HW;
    int tid = threadIdx.x;
    float s = 0.f, ss = 0.f;
    for (int i = tid; i < CPG * HW; i += 256) {
        float v = xp[i];
        s += v; ss += v * v;
    }
    __shared__ float red0[4], red1[4];
    for (int off = 32; off > 0; off >>= 1) {
        s  += __shfl_down(s, off);
        ss += __shfl_down(ss, off);
    }
    int wave = tid >> 6, lane = tid & 63;
    if (lane == 0) { red0[wave] = s; red1[wave] = ss; }
    __syncthreads();
    if (tid == 0) {
        float S  = red0[0] + red0[1] + red0[2] + red0[3];
        float SS = red1[0] + red1[1] + red1[2] + red1[3];
        float mean = S / (float)(CPG * HW);
        float var  = SS / (float)(CPG * HW) - mean * mean;
        gstats[bg * 2]     = mean;
        gstats[bg * 2 + 1] = rsqrtf(var + EPS);
    }
}

// ---------------- GroupNorm apply -> hnT[b][n][c], fully coalesced writes ----------------
__global__ __launch_bounds__(256) void gn_apply(const float* __restrict__ x,
                                                const float* __restrict__ gamma,
                                                const float* __restrict__ beta,
                                                const float* __restrict__ gstats,
                                                __bf16* __restrict__ hnT) {
    int b = blockIdx.y, n0 = blockIdx.x * 32;
    __shared__ __align__(16) __bf16 T[32 * 520];
    __shared__ float gl[512], bl[512], sm[32], sr[32];
    int tid = threadIdx.x;
    if (tid < 32) {
        sm[tid] = gstats[(b * 32 + tid) * 2];
        sr[tid] = gstats[(b * 32 + tid) * 2 + 1];
    }
    for (int i = tid; i < 512; i += 256) { gl[i] = gamma[i]; bl[i] = beta[i]; }
    __syncthreads();
    const float* xb = x + (size_t)b * Cc * HW + n0;
    for (int i = tid; i < 16384; i += 256) {
        int c = i >> 5, n = i & 31;
        float v = xb[(size_t)c * HW + n];
        int g = c >> 4;
        T[n * 520 + c] = (__bf16)((v - sm[g]) * sr[g] * gl[c] + bl[c]);
    }
    __syncthreads();
    __bf16* hb = hnT + ((size_t)b * HW + n0) * Cc;
    for (int j = tid; j < 2048; j += 256) {
        int n = j >> 6, ch = j & 63;
        *(bf16x8*)&hb[(size_t)n * Cc + ch * 8] = *(const bf16x8*)&T[n * 520 + ch * 8];
    }
}

// ---------------- MFMA GEMM: D[m][n] = sum_k P[m][k] * Q[n][k] ----------------
// MT = 16-row m-strips per wave (tile = MT*32 x 128). 4 waves in 2x2.
template<int MT, bool BIAS_COL, bool RESID_F32>
__global__ __launch_bounds__(256) void gemm_mfma(
    const __bf16* __restrict__ Pm, const __bf16* __restrict__ Qm,
    const float* __restrict__ bias, const float* __restrict__ resid,
    void* __restrict__ outv, size_t pStride, size_t qStride, size_t oStride, int oN,
    float scaleLo, int loCols) {
    __shared__ __align__(16) __bf16 As[MT * 32 * 64];
    __shared__ __align__(16) __bf16 Bs[128 * 64];
    int tid = threadIdx.x;
    int wv = tid >> 6, lane = tid & 63, ln = lane & 15, quad = lane >> 4;
    int b = blockIdx.z;
    int bm = blockIdx.y * (MT * 32), bn = blockIdx.x * 128;
    const __bf16* Pb = Pm + (size_t)b * pStride;
    const __bf16* Qb = Qm + (size_t)b * qStride;
    int wm = (wv >> 1) * (MT * 16), wn = (wv & 1) * 64;

    f32x4 acc[MT][4];
    #pragma unroll
    for (int i = 0; i < MT; ++i)
        #pragma unroll
        for (int j = 0; j < 4; ++j) acc[i][j] = (f32x4){0.f, 0.f, 0.f, 0.f};

    for (int k0 = 0; k0 < 512; k0 += 64) {
        __syncthreads();
        #pragma unroll
        for (int u = 0; u < MT; ++u) {
            int idx = u * 256 + tid;
            int r = idx >> 3, lc = idx & 7;
            int cg = lc ^ (r & 7);
            async16(Pb + (size_t)(bm + r) * 512 + k0 + cg * 8, &As[r * 64 + lc * 8]);
        }
        #pragma unroll
        for (int u = 0; u < 4; ++u) {
            int idx = u * 256 + tid;
            int r = idx >> 3, lc = idx & 7;
            int cg = lc ^ (r & 7);
            async16(Qb + (size_t)(bn + r) * 512 + k0 + cg * 8, &Bs[r * 64 + lc * 8]);
        }
        __syncthreads();
        bf16x8 af[MT][2], bff[4][2];
        #pragma unroll
        for (int mt = 0; mt < MT; ++mt) {
            int row = wm + mt * 16 + ln;
            #pragma unroll
            for (int h = 0; h < 2; ++h) {
                int cc = (h * 4 + quad) ^ (ln & 7);
                af[mt][h] = *(const bf16x8*)&As[row * 64 + cc * 8];
            }
        }
        #pragma unroll
        for (int nt = 0; nt < 4; ++nt) {
            int row = wn + nt * 16 + ln;
            #pragma unroll
            for (int h = 0; h < 2; ++h) {
                int cc = (h * 4 + quad) ^ (ln & 7);
                bff[nt][h] = *(const bf16x8*)&Bs[row * 64 + cc * 8];
            }
        }
        #pragma unroll
        for (int mt = 0; mt < MT; ++mt)
            #pragma unroll
            for (int nt = 0; nt < 4; ++nt) {
                acc[mt][nt] = __builtin_amdgcn_mfma_f32_16x16x32_bf16(af[mt][0], bff[nt][0], acc[mt][nt], 0, 0, 0);
                acc[mt][nt] = __builtin_amdgcn_mfma_f32_16x16x32_bf16(af[mt][1], bff[nt][1], acc[mt][nt], 0, 0, 0);
            }
    }

    if (RESID_F32) {
        float* out = (float*)outv + (size_t)b * oStride;
        const float* res = resid + (size_t)b * oStride;
        #pragma unroll
        for (int mt = 0; mt < MT; ++mt)
            #pragma unroll
            for (int r = 0; r < 4; ++r) {
                int row = bm + wm + mt * 16 + quad * 4 + r;
                float bv = bias[row];
                #pragma unroll
                for (int nt = 0; nt < 4; ++nt) {
                    int col = bn + wn + nt * 16 + ln;
                    size_t idx = (size_t)row * oN + col;
                    out[idx] = acc[mt][nt][r] + bv + res[idx];
                }
            }
    } else {
        __bf16* out = (__bf16*)outv + (size_t)b * oStride;
        float bcol[4], scol[4];
        if (BIAS_COL) {
            #pragma unroll
            for (int nt = 0; nt < 4; ++nt) {
                int col = bn + wn + nt * 16 + ln;
                bcol[nt] = bias[col];
                scol[nt] = (col < loCols) ? scaleLo : 1.0f;
            }
        }
        #pragma unroll
        for (int mt = 0; mt < MT; ++mt)
            #pragma unroll
            for (int r = 0; r < 4; ++r) {
                int row = bm + wm + mt * 16 + quad * 4 + r;
                float brow = BIAS_COL ? 0.f : bias[row];
                #pragma unroll
                for (int nt = 0; nt < 4; ++nt) {
                    int col = bn + wn + nt * 16 + ln;
                    float v = BIAS_COL ? (acc[mt][nt][r] + bcol[nt]) * scol[nt]
                                       : acc[mt][nt][r] + brow;
                    out[(size_t)row * oN + col] = (__bf16)v;
                }
            }
    }
}

// ---------------- Flash attention, K-split x2, max-free softmax ----------------
// Grid (8 qblocks, 64 bh, 2 ksplit). Each block: 8 K-tiles of its half.
// Writes unnormalized bf16 partial O + f32 partial row-sum; combine kernel finishes.
__global__ __launch_bounds__(256) void attn_mfma(const __bf16* __restrict__ qkT,
                                                 const __bf16* __restrict__ vbuf,
                                                 __bf16* __restrict__ Opart,
                                                 float* __restrict__ lpart) {
    __shared__ __align__(16) __bf16 Ks[64 * 64];
    __shared__ __align__(16) __bf16 Vs[64 * 64];
    int tid = threadIdx.x;
    int wv = tid >> 6, lane = tid & 63, ln = lane & 15, quad = lane >> 4;
    int bh = blockIdx.y;
    int b = bh >> 3, h = bh & 7;
    int ks = blockIdx.z;
    int i0 = blockIdx.x * 128 + wv * 32;

    const __bf16* qbase = qkT + ((size_t)b * HW + i0 + ln) * 1024 + h * HD + quad * 8;
    bf16x8 qf[2][2];
    #pragma unroll
    for (int mt = 0; mt < 2; ++mt) {
        qf[mt][0] = *(const bf16x8*)(qbase + (size_t)mt * 16 * 1024);
        qf[mt][1] = *(const bf16x8*)(qbase + (size_t)mt * 16 * 1024 + 32);
    }

    f32x4 oacc[2][4];
    #pragma unroll
    for (int mt = 0; mt < 2; ++mt)
        #pragma unroll
        for (int ct = 0; ct < 4; ++ct) oacc[mt][ct] = (f32x4){0.f, 0.f, 0.f, 0.f};
    float lsum[2] = {0.f, 0.f};

    for (int kt = ks * 8; kt < ks * 8 + 8; ++kt) {
        int kb = kt * 64;
        __syncthreads();
        #pragma unroll
        for (int u = 0; u < 2; ++u) {
            int idx = u * 256 + tid;
            int r = idx >> 3, lc = idx & 7;
            int cg = lc ^ (r & 7);
            async16(qkT + ((size_t)b * HW + kb + r) * 1024 + 512 + h * HD + cg * 8,
                    Ks + idx * 8);
            async16(vbuf + ((size_t)b * Cc + h * HD + r) * HW + kb + cg * 8,
                    Vs + idx * 8);
        }
        __syncthreads();

        f32x4 st[2][4];
        #pragma unroll
        for (int jt = 0; jt < 4; ++jt) {
            int row = jt * 16 + ln;
            int c0 = quad ^ (ln & 7);
            int c1 = (4 + quad) ^ (ln & 7);
            bf16x8 kf0 = *(const bf16x8*)&Ks[row * 64 + c0 * 8];
            bf16x8 kf1 = *(const bf16x8*)&Ks[row * 64 + c1 * 8];
            #pragma unroll
            for (int mt = 0; mt < 2; ++mt) {
                f32x4 s = (f32x4){0.f, 0.f, 0.f, 0.f};
                s = __builtin_amdgcn_mfma_f32_16x16x32_bf16(kf0, qf[mt][0], s, 0, 0, 0);
                s = __builtin_amdgcn_mfma_f32_16x16x32_bf16(kf1, qf[mt][1], s, 0, 0, 0);
                st[mt][jt] = s;
            }
        }

        bf16x4 pk[2][4];
        #pragma unroll
        for (int mt = 0; mt < 2; ++mt)
            #pragma unroll
            for (int jt = 0; jt < 4; ++jt) {
                float p0 = exp2f(st[mt][jt][0]);
                float p1 = exp2f(st[mt][jt][1]);
                float p2 = exp2f(st[mt][jt][2]);
                float p3 = exp2f(st[mt][jt][3]);
                lsum[mt] += (p0 + p1) + (p2 + p3);
                pk[mt][jt] = (bf16x4){(__bf16)p0, (__bf16)p1, (__bf16)p2, (__bf16)p3};
            }

        #pragma unroll
        for (int ct = 0; ct < 4; ++ct) {
            int row = ct * 16 + ln;
            bf16x4 vf[4];
            #pragma unroll
            for (int kss = 0; kss < 4; ++kss) {
                int cc16 = (kss * 2 + (quad >> 1)) ^ (ln & 7);
                vf[kss] = *(const bf16x4*)&Vs[row * 64 + cc16 * 8 + (quad & 1) * 4];
            }
            #pragma unroll
            for (int mt = 0; mt < 2; ++mt)
                #pragma unroll
                for (int kss = 0; kss < 4; ++kss)
                    oacc[mt][ct] = mfma16(vf[kss], pk[mt][kss], oacc[mt][ct]);
        }
    }

    #pragma unroll
    for (int mt = 0; mt < 2; ++mt) {
        lsum[mt] += __shfl_xor(lsum[mt], 16);
        lsum[mt] += __shfl_xor(lsum[mt], 32);
        if (lane < 16)
            lpart[(size_t)ks * 65536 + (size_t)bh * 1024 + i0 + mt * 16 + lane] = lsum[mt];
        __bf16* op = Opart + (size_t)ks * 4194304 +
                     ((size_t)b * HW + i0 + mt * 16 + ln) * Cc + h * HD + quad * 4;
        #pragma unroll
        for (int ct = 0; ct < 4; ++ct) {
            bf16x4 o = { (__bf16)oacc[mt][ct][0], (__bf16)oacc[mt][ct][1],
                         (__bf16)oacc[mt][ct][2], (__bf16)oacc[mt][ct][3] };
            *(bf16x4*)(op + ct * 16) = o;
        }
    }
}

// ---------------- Combine split-K partials: attnT = (O0+O1)/(l0+l1) ----------------
__global__ __launch_bounds__(256) void attn_combine(const __bf16* __restrict__ Opart,
                                                    const float* __restrict__ lpart,
                                                    __bf16* __restrict__ attnT) {
    int gid = blockIdx.x * 256 + threadIdx.x;       // 524288 threads, 8 elems each
    size_t base = (size_t)gid * 8;
    int b = gid >> 16;
    int rem = gid & 65535;
    int n = rem >> 6;
    int h = (rem & 63) >> 3;
    float l0 = lpart[((size_t)b * 8 + h) * 1024 + n];
    float l1 = lpart[65536 + ((size_t)b * 8 + h) * 1024 + n];
    float rl = 1.f / (l0 + l1);
    bf16x8 p0 = *(const bf16x8*)(Opart + base);
    bf16x8 p1 = *(const bf16x8*)(Opart + 4194304 + base);
    bf16x8 o;
    #pragma unroll
    for (int t = 0; t < 8; ++t)
        o[t] = (__bf16)(((float)p0[t] + (float)p1[t]) * rl);
    *(bf16x8*)(attnT + base) = o;
}

extern "C" void kernel_launch(void* const* d_in, const int* in_sizes, int n_in,
                              void* d_out, int out_size, void* d_ws, size_t ws_size,
                              hipStream_t stream) {
    const float* x      = (const float*)d_in[0];
    const float* gamma  = (const float*)d_in[1];
    const float* beta   = (const float*)d_in[2];
    const float* w_qkv  = (const float*)d_in[3];
    const float* b_qkv  = (const float*)d_in[4];
    const float* w_proj = (const float*)d_in[5];
    const float* b_proj = (const float*)d_in[6];
    float* out = (float*)d_out;

    __bf16* wq_bf  = (__bf16*)d_ws;                       // 786432
    __bf16* wp_bf  = wq_bf + (size_t)1536 * 512;          // 262144
    __bf16* hnT    = wp_bf + (size_t)512 * 512;           // 4194304
    __bf16* qkT    = hnT + (size_t)Bn * HW * Cc;          // 8388608
    __bf16* vbuf   = qkT + (size_t)Bn * HW * 1024;        // 4194304
    __bf16* attnT  = vbuf + (size_t)Bn * Cc * HW;         // 4194304
    __bf16* Opart  = attnT + (size_t)Bn * HW * Cc;        // 2 x 4194304
    float*  lpart  = (float*)(Opart + (size_t)2 * Bn * HW * Cc);  // 2 x 65536 f32
    float*  gstats = lpart + 131072;                      // 512 f32

    conv_kernel<<<1024, 256, 0, stream>>>(w_qkv, wq_bf, 196608, w_proj, wp_bf, 65536);

    gn_stats<<<Bn * GROUPS, 256, 0, stream>>>(x, gstats);
    dim3 gga(32, Bn);
    gn_apply<<<gga, 256, 0, stream>>>(x, gamma, beta, gstats, hnT);

    // QK: D[n][o] = sum_c hnT[n][c] * w_qkv[o][c] + b_qkv[o]; Q cols (<512) pre-scaled
    const float QSCALE = 0.125f * 1.44269504088896f;  // hd^-0.5 * log2(e)
    dim3 gqk(8, 16, Bn);
    gemm_mfma<2, true, false><<<gqk, 256, 0, stream>>>(
        hnT, wq_bf, b_qkv, nullptr, qkT,
        (size_t)HW * Cc, 0, (size_t)HW * 1024, 1024, QSCALE, 512);

    // V: D[vo][n] = sum_c w_qkv[1024+vo][c] * hnT[n][c] + b_qkv[1024+vo]
    dim3 gv(8, 8, Bn);
    gemm_mfma<2, false, false><<<gv, 256, 0, stream>>>(
        wq_bf + (size_t)1024 * 512, hnT, b_qkv + 1024, nullptr, vbuf,
        0, (size_t)HW * Cc, (size_t)Cc * HW, 1024, 1.0f, 0);

    dim3 ga(8, 64, 2);
    attn_mfma<<<ga, 256, 0, stream>>>(qkT, vbuf, Opart, lpart);
    attn_combine<<<2048, 256, 0, stream>>>(Opart, lpart, attnT);

    // proj: D[o][n] = sum_c w_proj[o][c] * attnT[n][c] + b_proj[o] + x
    dim3 gp(8, 8, Bn);
    gemm_mfma<2, false, true><<<gp, 256, 0, stream>>>(
        wp_bf, attnT, b_proj, x, out,
        0, (size_t)HW * Cc, (size_t)Cc * HW, 1024, 1.0f, 0);
}